// Round 14
// baseline (339.607 us; speedup 1.0000x reference)
//
#include <hip/hip_runtime.h>
#include <hip/hip_bf16.h>

typedef unsigned short u16;
typedef unsigned int   u32;

#define N_NODES 10000
#define N_EDGES 160000
#define HDIM    512
#define KDIM    1024
#define NPAD    10112   // 79 * 128

typedef __attribute__((ext_vector_type(8))) __bf16 bf16x8;
typedef __attribute__((ext_vector_type(4))) float  f32x4;

__device__ __forceinline__ float bflo(u32 v){ return __builtin_bit_cast(float, v << 16); }
__device__ __forceinline__ float bfhi(u32 v){ return __builtin_bit_cast(float, v & 0xffff0000u); }
__device__ __forceinline__ u16   f2bf(float f){ __hip_bfloat16 h = __float2bfloat16(f); return __builtin_bit_cast(u16, h); }

// ---------------- CSR build ----------------
__global__ void k_hist(const int* __restrict__ dst, int* __restrict__ cnt){
  int e = blockIdx.x*256 + threadIdx.x;
  if (e < N_EDGES) atomicAdd(&cnt[dst[e]], 1);
}

__global__ __launch_bounds__(1024) void k_scan(const int* __restrict__ cnt, int* __restrict__ row_ptr,
                                               int* __restrict__ cursor, float* __restrict__ inv_deg){
  __shared__ int part[1024];
  int t = threadIdx.x;
  int base = t*10;
  int local[10]; int s = 0;
  for (int i=0;i<10;i++){
    int idx = base+i;
    int v = (idx < N_NODES) ? cnt[idx] : 0;
    local[i] = s; s += v;
  }
  part[t] = s;
  __syncthreads();
  for (int off=1; off<1024; off<<=1){
    int v = (t>=off) ? part[t-off] : 0;
    __syncthreads();
    part[t] += v;
    __syncthreads();
  }
  int prev = (t==0) ? 0 : part[t-1];
  for (int i=0;i<10;i++){
    int idx = base+i;
    if (idx < N_NODES){
      int rp = prev + local[i];
      row_ptr[idx] = rp; cursor[idx] = rp;
      int c = cnt[idx];
      inv_deg[idx] = 1.0f / (float)(c > 0 ? c : 1);
    }
  }
  if (t==1023) row_ptr[N_NODES] = part[1023];
}

__global__ void k_fill(const int* __restrict__ src, const int* __restrict__ dst,
                       int* __restrict__ cursor, int* __restrict__ csr_src){
  int e = blockIdx.x*256 + threadIdx.x;
  if (e < N_EDGES){
    int pos = atomicAdd(&cursor[dst[e]], 1);
    csr_src[pos] = src[e];
  }
}

// ---------------- prep: wcat (fp32->bf16 concat) + copy_x + zero scratch ----------------
#define NZERO 14656   // cnt(10048) + stats(4096) + bias0(512)
__global__ __launch_bounds__(256) void k_prep(const float* __restrict__ wpr, const float* __restrict__ wpo,
                                              const float* __restrict__ wrel, const float* __restrict__ wroot,
                                              const float* __restrict__ wfr, const float* __restrict__ wfo,
                                              const float* __restrict__ x,
                                              u16* __restrict__ Wcat, u16* __restrict__ Wfin,
                                              u16* __restrict__ A, u32* __restrict__ zreg){
  int b = blockIdx.x, t = threadIdx.x;
  if (b < 4096){
    int i = b*256 + t;
    int lyr = i >> 18;
    int r   = i & 262143;
    int o = r >> 9, k = r & 511;
    const float* R = (lyr==0) ? wpr : wrel  + (size_t)(lyr-1)*262144;
    const float* O = (lyr==0) ? wpo : wroot + (size_t)(lyr-1)*262144;
    Wcat[(size_t)lyr*524288 + (size_t)o*KDIM + k]        = f2bf(R[r]);
    Wcat[(size_t)lyr*524288 + (size_t)o*KDIM + HDIM + k] = f2bf(O[r]);
    if (i < 10*512){
      int oo = i >> 9, kk = i & 511;
      Wfin[oo*KDIM + kk]        = f2bf(wfr[i]);
      Wfin[oo*KDIM + HDIM + kk] = f2bf(wfo[i]);
    }
  } else if (b < 9096){
    int c = (b-4096)*256 + t;
    int n = c >> 7, o = (c & 127)*4;
    float4 v = *(const float4*)(x + (size_t)n*HDIM + o);
    ushort4 bb;
    bb.x = f2bf(v.x); bb.y = f2bf(v.y); bb.z = f2bf(v.z); bb.w = f2bf(v.w);
    *(ushort4*)(A + (size_t)n*KDIM + HDIM + o) = bb;
  } else {
    int i = (b-9096)*256 + t;
    if (i < NZERO) zreg[i] = 0u;
  }
}

// ================= XCD-paneled agg core =================
__device__ __forceinline__ void agg_panel2(int n, int pc, int li, const u16* __restrict__ Abuf,
                                           const int* __restrict__ row_ptr, const int* __restrict__ cnt,
                                           const int* __restrict__ csr, const float* __restrict__ inv_deg,
                                           float* __restrict__ a){
  int start = row_ptr[n], num = cnt[n];
  const u16* base = Abuf + HDIM + pc*128 + li*4;
  a[0]=0.f; a[1]=0.f; a[2]=0.f; a[3]=0.f;
  int s[8];
  #pragma unroll
  for (int i=0;i<8;i++) s[i] = (i < num) ? csr[start+i] : 0;
  int j = 0;
  while (j + 8 <= num){
    int cur[8];
    #pragma unroll
    for (int i=0;i<8;i++) cur[i] = s[i];
    int jn = j + 8;
    #pragma unroll
    for (int i=0;i<8;i++) s[i] = (jn+i < num) ? csr[start+jn+i] : 0;
    #pragma unroll
    for (int i=0;i<8;i++){
      uint2 v = *(const uint2*)(base + (size_t)cur[i]*KDIM);
      a[0]+=bflo(v.x); a[1]+=bfhi(v.x); a[2]+=bflo(v.y); a[3]+=bfhi(v.y);
    }
    j = jn;
  }
  #pragma unroll
  for (int i=0;i<8;i++){
    if (j+i < num){
      uint2 v = *(const uint2*)(base + (size_t)s[i]*KDIM);
      a[0]+=bflo(v.x); a[1]+=bfhi(v.x); a[2]+=bflo(v.y); a[3]+=bfhi(v.y);
    }
  }
  float id = inv_deg[n];
  #pragma unroll
  for (int i=0;i<4;i++) a[i] *= id;
}

// wscale row with fused BN finalize (whole block per row)
__device__ __forceinline__ void wscale_row(int o, const u16* __restrict__ Wsrc, const float* __restrict__ stats,
                                           const float* __restrict__ gamma, const float* __restrict__ beta,
                                           int layer, u16* __restrict__ Wdst, float* __restrict__ biasOut){
  __shared__ float wred[4];
  int t = threadIdx.x, l = t & 63, w = t >> 6;
  int k = t*4;
  int fk = k & 511;
  float a[4], b[4];
  #pragma unroll
  for (int i=0;i<4;i++){
    int f = fk + i;
    float mu  = stats[f] * (1.f/N_NODES);
    float var = stats[512+f] * (1.f/N_NODES) - mu*mu;
    float rs  = rsqrtf(var + 1e-5f);
    float g = gamma[layer*512+f];
    a[i] = g*rs;
    b[i] = beta[layer*512+f] - mu*a[i];
  }
  const u16* row = Wsrc + (size_t)o*KDIM;
  uint2 v = *(const uint2*)(row + k);
  float f0 = bflo(v.x), f1 = bfhi(v.x), f2 = bflo(v.y), f3 = bfhi(v.y);
  u16 od[4];
  od[0]=f2bf(f0*a[0]); od[1]=f2bf(f1*a[1]); od[2]=f2bf(f2*a[2]); od[3]=f2bf(f3*a[3]);
  *(ushort4*)(Wdst + (size_t)o*KDIM + k) = *(ushort4*)od;
  float bsum = f0*b[0] + f1*b[1] + f2*b[2] + f3*b[3];
  #pragma unroll
  for (int off=32; off; off>>=1) bsum += __shfl_down(bsum, off);
  if (l==0) wred[w] = bsum;
  __syncthreads();
  if (t==0) biasOut[o] = wred[0]+wred[1]+wred[2]+wred[3];
}

// ---------------- XCD-paneled agg: grid 5000 1D; pc = id&3 ----------------
__global__ __launch_bounds__(256) void k_agg(const u16* __restrict__ Abuf,
                                             const int* __restrict__ row_ptr, const int* __restrict__ cnt,
                                             const int* __restrict__ csr, const float* __restrict__ inv_deg,
                                             u16* __restrict__ Aleft){
  int id = blockIdx.x;
  int pc = id & 3, g = id >> 2;
  int t = threadIdx.x, w = t >> 6, l = t & 63, hf = l >> 5, li = l & 31;
  int n = g*8 + w*2 + hf;
  float a[4];
  agg_panel2(n, pc, li, Abuf, row_ptr, cnt, csr, inv_deg, a);
  ushort4 ob;
  ob.x = f2bf(a[0]); ob.y = f2bf(a[1]); ob.z = f2bf(a[2]); ob.w = f2bf(a[3]);
  *(ushort4*)(Aleft + (size_t)n*KDIM + pc*128 + li*4) = ob;
}

// ---------------- XCD-paneled agg + wscale (blocks id<512 scale weight row id) ----------------
__global__ __launch_bounds__(256) void k_aggws(const u16* __restrict__ Abuf,
                                               const int* __restrict__ row_ptr, const int* __restrict__ cnt,
                                               const int* __restrict__ csr, const float* __restrict__ inv_deg,
                                               u16* __restrict__ Aleft,
                                               const u16* __restrict__ Wsrc, const float* __restrict__ stats,
                                               const float* __restrict__ gamma, const float* __restrict__ beta,
                                               int layer, u16* __restrict__ Wdst, float* __restrict__ biasOut){
  int id = blockIdx.x;
  if (id < 512)
    wscale_row(id, Wsrc, stats, gamma, beta, layer, Wdst, biasOut);
  int pc = id & 3, g = id >> 2;
  int t = threadIdx.x, w = t >> 6, l = t & 63, hf = l >> 5, li = l & 31;
  int n = g*8 + w*2 + hf;
  float a[4];
  agg_panel2(n, pc, li, Abuf, row_ptr, cnt, csr, inv_deg, a);
  ushort4 ob;
  ob.x = f2bf(a[0]); ob.y = f2bf(a[1]); ob.z = f2bf(a[2]); ob.w = f2bf(a[3]);
  *(ushort4*)(Aleft + (size_t)n*KDIM + pc*128 + li*4) = ob;
}

// ---------------- k_pq: project h3 to 20 dims with inline BN-fold ----------------
// P[n][c] = sum_k (a[k]*h3raw[n][k]+b[k]) * Wfr[c][k]   (to be aggregated)
// Q[n][c] = same with Wfo. Wave per node, lane l owns cols 8l..8l+7.
__global__ __launch_bounds__(256) void k_pq(const u16* __restrict__ A,
                                            const u16* __restrict__ Wfin,
                                            const float* __restrict__ stats,
                                            const float* __restrict__ gamma, const float* __restrict__ beta,
                                            float* __restrict__ P, float* __restrict__ Q){
  __shared__ float sa[512], sb[512];
  __shared__ __align__(16) u16 sw[20*512];
  int t = threadIdx.x, w = t >> 6, l = t & 63;
  for (int k = t; k < 512; k += 256){
    float mu  = stats[k] * (1.f/N_NODES);
    float var = stats[512+k] * (1.f/N_NODES) - mu*mu;
    float rs  = rsqrtf(var + 1e-5f);
    float g = gamma[3*512+k];
    sa[k] = g*rs;
    sb[k] = beta[3*512+k] - mu*g*rs;
  }
  for (int i = t; i < 1280; i += 256){      // 1280 groups of 8 u16
    int c = (i*8) >> 9;
    int k = (i*8) & 511;
    const u16* srcp = (c < 10) ? (Wfin + (size_t)c*KDIM + k)
                               : (Wfin + (size_t)(c-10)*KDIM + HDIM + k);
    *(uint4*)(sw + i*8) = *(const uint4*)srcp;
  }
  __syncthreads();
  int n = blockIdx.x*4 + w;
  uint4 vh = *(const uint4*)(A + (size_t)n*KDIM + HDIM + l*8);
  float hh[8];
  {
    float hr[8] = { bflo(vh.x), bfhi(vh.x), bflo(vh.y), bfhi(vh.y),
                    bflo(vh.z), bfhi(vh.z), bflo(vh.w), bfhi(vh.w) };
    #pragma unroll
    for (int i=0;i<8;i++) hh[i] = hr[i]*sa[l*8+i] + sb[l*8+i];
  }
  float acc[20];
  #pragma unroll
  for (int c=0;c<20;c++){
    uint4 wv = *(const uint4*)(sw + c*512 + l*8);
    acc[c] = hh[0]*bflo(wv.x)+hh[1]*bfhi(wv.x)+hh[2]*bflo(wv.y)+hh[3]*bfhi(wv.y)
           + hh[4]*bflo(wv.z)+hh[5]*bfhi(wv.z)+hh[6]*bflo(wv.w)+hh[7]*bfhi(wv.w);
  }
  #pragma unroll
  for (int c=0;c<20;c++)
    #pragma unroll
    for (int off=32; off; off>>=1)
      acc[c] += __shfl_down(acc[c], off);
  if (l == 0){
    #pragma unroll
    for (int c=0;c<10;c++) P[n*10+c] = acc[c];
    #pragma unroll
    for (int c=0;c<10;c++) Q[n*10+c] = acc[10+c];
  }
}

// ---------------- k_aggout: mean-gather P (40B rows) + Q + log_softmax ----------------
__global__ __launch_bounds__(256) void k_aggout(const float* __restrict__ P, const float* __restrict__ Q,
                                                const int* __restrict__ row_ptr, const int* __restrict__ cnt,
                                                const int* __restrict__ csr, const float* __restrict__ inv_deg,
                                                float* __restrict__ out){
  __shared__ float red[4][12];
  int t = threadIdx.x, w = t >> 6, l = t & 63;
  int n = blockIdx.x*4 + w;
  float acc = 0.f;
  if (l < 10){
    int start = row_ptr[n], num = cnt[n];
    int s0 = (0 < num) ? csr[start] : 0;
    int s1 = (1 < num) ? csr[start+1] : 0;
    int j = 0;
    while (j + 2 <= num){
      int t0 = s0, t1 = s1;
      if (j+2 < num) s0 = csr[start+j+2];
      if (j+3 < num) s1 = csr[start+j+3];
      acc += P[t0*10 + l] + P[t1*10 + l];
      j += 2;
    }
    if (j < num) acc += P[s0*10 + l];
    acc = acc * inv_deg[n] + Q[n*10 + l];
    red[w][l] = acc;
  }
  __syncthreads();
  if (l == 0){
    float m = red[w][0];
    #pragma unroll
    for (int cc=1;cc<10;cc++) m = fmaxf(m, red[w][cc]);
    float s = 0.f;
    #pragma unroll
    for (int cc=0;cc<10;cc++) s += expf(red[w][cc]-m);
    red[w][10] = m + logf(s);
  }
  __syncthreads();
  if (l < 10) out[n*10 + l] = acc - red[w][10];
}

// ---------------- GEMM 64x128 tile, BK=64 (2 k-halves per barrier), XCD A-partition ----------------
__global__ __launch_bounds__(256) void k_gemm(const u16* __restrict__ A, const u16* __restrict__ W,
                                              const float* __restrict__ bias,
                                              u16* __restrict__ Hout, float* __restrict__ stats){
  __shared__ __align__(16) u16 As[2*64*32];    // 8 KB
  __shared__ __align__(16) u16 Bs[2*128*32];   // 16 KB
  __shared__ float red_s[2][128];
  __shared__ float red_q[2][128];
  const int id  = blockIdx.x;
  const int xcd = id & 7;
  const int j   = id >> 3;
  const int m_idx = xcd*20 + (j>>2);
  const int pc  = j & 3;
  if (m_idx >= 158) return;
  const int t  = threadIdx.x;
  const int l  = t & 63;
  const int wv = t >> 6;
  const int wm = wv >> 1, wn = wv & 1;
  const int m0 = m_idx * 64;
  const int n0 = pc * 128;

  const int c1 = t + 256;
  const size_t gA  = (size_t)(m0 + (t>>2))*KDIM + ((t&3)*8);
  const size_t gB0 = (size_t)(n0 + (t>>2))*KDIM + ((t&3)*8);
  const size_t gB1 = (size_t)(n0 + (c1>>2))*KDIM + ((c1&3)*8);

  f32x4 acc[2][4];
  #pragma unroll
  for (int i=0;i<2;i++)
    #pragma unroll
    for (int jj=0;jj<4;jj++)
      acc[i][jj] = f32x4{0.f,0.f,0.f,0.f};

  const int aoff = (wm*32 + (l&15))*32 + (l>>4)*8;
  const int boff = (wn*64 + (l&15))*32 + (l>>4)*8;

  for (int k0 = 0; k0 < KDIM; k0 += 64){
    #pragma unroll
    for (int kh = 0; kh < 2; kh++){
      __builtin_amdgcn_global_load_lds((const __attribute__((address_space(1))) void*)(A + gA + k0 + kh*32),
                                       (__attribute__((address_space(3))) void*)(As + kh*2048 + t*8), 16, 0, 0);
      __builtin_amdgcn_global_load_lds((const __attribute__((address_space(1))) void*)(W + gB0 + k0 + kh*32),
                                       (__attribute__((address_space(3))) void*)(Bs + kh*4096 + t*8), 16, 0, 0);
      __builtin_amdgcn_global_load_lds((const __attribute__((address_space(1))) void*)(W + gB1 + k0 + kh*32),
                                       (__attribute__((address_space(3))) void*)(Bs + kh*4096 + c1*8), 16, 0, 0);
    }
    __syncthreads();
    #pragma unroll
    for (int kh = 0; kh < 2; kh++){
      bf16x8 af[2], bfr[4];
      af[0] = *(const bf16x8*)(As + kh*2048 + aoff);
      af[1] = *(const bf16x8*)(As + kh*2048 + aoff + 16*32);
      #pragma unroll
      for (int nt=0; nt<4; nt++)
        bfr[nt] = *(const bf16x8*)(Bs + kh*4096 + boff + nt*16*32);
      #pragma unroll
      for (int mt=0; mt<2; mt++)
        #pragma unroll
        for (int nt=0; nt<4; nt++)
          acc[mt][nt] = __builtin_amdgcn_mfma_f32_16x16x32_bf16(af[mt], bfr[nt], acc[mt][nt], 0, 0, 0);
    }
    __syncthreads();
  }

  float bi[4], sc[4], qc[4];
  #pragma unroll
  for (int nt=0; nt<4; nt++){
    bi[nt] = bias[n0 + wn*64 + nt*16 + (l & 15)];
    sc[nt] = 0.f; qc[nt] = 0.f;
  }
  #pragma unroll
  for (int nt=0; nt<4; nt++){
    const int col = n0 + wn*64 + nt*16 + (l & 15);
    #pragma unroll
    for (int mt=0; mt<2; mt++){
      #pragma unroll
      for (int r=0; r<4; r++){
        const int row = m0 + wm*32 + mt*16 + (l>>4)*4 + r;
        if (row < N_NODES){
          float v = acc[mt][nt][r] + bi[nt];
          v = v > 0.f ? v : 0.f;
          sc[nt] += v; qc[nt] += v*v;
          Hout[(size_t)row*KDIM + HDIM + col] = f2bf(v);
        }
      }
    }
  }
  #pragma unroll
  for (int nt=0; nt<4; nt++){
    float s = sc[nt], q = qc[nt];
    s += __shfl_xor(s, 16); s += __shfl_xor(s, 32);
    q += __shfl_xor(q, 16); q += __shfl_xor(q, 32);
    if (l < 16){
      red_s[wm][wn*64 + nt*16 + l] = s;
      red_q[wm][wn*64 + nt*16 + l] = q;
    }
  }
  __syncthreads();
  if (t < 128){
    atomicAdd(&stats[n0 + t],       red_s[0][t] + red_s[1][t]);
    atomicAdd(&stats[512 + n0 + t], red_q[0][t] + red_q[1][t]);
  }
}

extern "C" void kernel_launch(void* const* d_in, const int* in_sizes, int n_in,
                              void* d_out, int out_size, void* d_ws, size_t ws_size,
                              hipStream_t stream){
  (void)in_sizes; (void)n_in; (void)out_size; (void)ws_size;
  const float* x     = (const float*)d_in[0];
  const int*   eidx  = (const int*)d_in[1];
  const float* wpr   = (const float*)d_in[2];
  const float* wpo   = (const float*)d_in[3];
  const float* wrel  = (const float*)d_in[4];
  const float* wroot = (const float*)d_in[5];
  const float* gamma = (const float*)d_in[6];
  const float* beta  = (const float*)d_in[7];
  const float* wfr   = (const float*)d_in[8];
  const float* wfo   = (const float*)d_in[9];
  const int* src  = eidx;
  const int* dstv = eidx + N_EDGES;

  char* p = (char*)d_ws;
  auto carve = [&](size_t b){ char* q = p; p += (b + 255) & ~(size_t)255; return q; };
  u16*  A0      = (u16*)carve((size_t)NPAD*KDIM*2);
  u16*  A1      = (u16*)carve((size_t)NPAD*KDIM*2);
  u16*  Wcat    = (u16*)carve((size_t)4*HDIM*KDIM*2);
  u16*  Wfin    = (u16*)carve((size_t)10*KDIM*2);
  u16*  Wsc     = (u16*)carve((size_t)HDIM*KDIM*2);
  int*   zreg   = (int*)carve((size_t)NZERO*4);
  int*   cnt    = zreg;
  float* stats  = (float*)(zreg + 10048);
  float* bias0  = (float*)(zreg + 10048 + 4096);
  int*  row_ptr = (int*)carve((N_NODES+1)*4);
  int*  cursor  = (int*)carve(N_NODES*4);
  int*  csr     = (int*)carve(N_EDGES*4);
  float* inv_deg= (float*)carve(N_NODES*4);
  float* biasN  = (float*)carve(512*4);
  float* Pb     = (float*)carve((size_t)N_NODES*10*4);
  float* Qb     = (float*)carve((size_t)N_NODES*10*4);
  float* outp   = (float*)d_out;

  k_prep<<<9154, 256, 0, stream>>>(wpr, wpo, wrel, wroot, wfr, wfo, x, Wcat, Wfin, A0, (u32*)zreg);
  k_hist<<<(N_EDGES+255)/256, 256, 0, stream>>>(dstv, cnt);
  k_scan<<<1, 1024, 0, stream>>>(cnt, row_ptr, cursor, inv_deg);
  k_fill<<<(N_EDGES+255)/256, 256, 0, stream>>>(src, dstv, cursor, csr);
  k_agg<<<5000, 256, 0, stream>>>(A0, row_ptr, cnt, csr, inv_deg, A0);

  u16* Ain = A0; u16* Aout = A1;
  for (int lyr=0; lyr<4; lyr++){
    const u16* Wthis = (lyr==0) ? Wcat : Wsc;
    const float* bthis = (lyr==0) ? bias0 : biasN;
    k_gemm<<<640, 256, 0, stream>>>(Ain, Wthis, bthis, Aout, stats + lyr*1024);
    if (lyr < 3){
      k_aggws<<<5000, 256, 0, stream>>>(Aout, row_ptr, cnt, csr, inv_deg, Aout,
                                        Wcat + (size_t)(lyr+1)*HDIM*KDIM, stats + lyr*1024,
                                        gamma, beta, lyr, Wsc, biasN);
    } else {
      k_pq<<<2500, 256, 0, stream>>>(Aout, Wfin, stats + lyr*1024, gamma, beta, Pb, Qb);
      k_aggout<<<2500, 256, 0, stream>>>(Pb, Qb, row_ptr, cnt, csr, inv_deg, outp);
    }
    u16* tmp = Ain; Ain = Aout; Aout = tmp;
  }
}

// Round 15
// 334.178 us; speedup vs baseline: 1.0162x; 1.0162x over previous
//
#include <hip/hip_runtime.h>
#include <hip/hip_bf16.h>

typedef unsigned short u16;
typedef unsigned int   u32;

#define N_NODES 10000
#define N_EDGES 160000
#define HDIM    512
#define KDIM    1024
#define NPAD    10112   // 79 * 128

typedef __attribute__((ext_vector_type(8))) __bf16 bf16x8;
typedef __attribute__((ext_vector_type(4))) float  f32x4;

__device__ __forceinline__ float bflo(u32 v){ return __builtin_bit_cast(float, v << 16); }
__device__ __forceinline__ float bfhi(u32 v){ return __builtin_bit_cast(float, v & 0xffff0000u); }
__device__ __forceinline__ u16   f2bf(float f){ __hip_bfloat16 h = __float2bfloat16(f); return __builtin_bit_cast(u16, h); }

// ---------------- CSR build ----------------
__global__ void k_hist(const int* __restrict__ dst, int* __restrict__ cnt){
  int e = blockIdx.x*256 + threadIdx.x;
  if (e < N_EDGES) atomicAdd(&cnt[dst[e]], 1);
}

__global__ __launch_bounds__(1024) void k_scan(const int* __restrict__ cnt, int* __restrict__ row_ptr,
                                               int* __restrict__ cursor, float* __restrict__ inv_deg){
  __shared__ int part[1024];
  int t = threadIdx.x;
  int base = t*10;
  int local[10]; int s = 0;
  for (int i=0;i<10;i++){
    int idx = base+i;
    int v = (idx < N_NODES) ? cnt[idx] : 0;
    local[i] = s; s += v;
  }
  part[t] = s;
  __syncthreads();
  for (int off=1; off<1024; off<<=1){
    int v = (t>=off) ? part[t-off] : 0;
    __syncthreads();
    part[t] += v;
    __syncthreads();
  }
  int prev = (t==0) ? 0 : part[t-1];
  for (int i=0;i<10;i++){
    int idx = base+i;
    if (idx < N_NODES){
      int rp = prev + local[i];
      row_ptr[idx] = rp; cursor[idx] = rp;
      int c = cnt[idx];
      inv_deg[idx] = 1.0f / (float)(c > 0 ? c : 1);
    }
  }
  if (t==1023) row_ptr[N_NODES] = part[1023];
}

__global__ void k_fill(const int* __restrict__ src, const int* __restrict__ dst,
                       int* __restrict__ cursor, int* __restrict__ csr_src){
  int e = blockIdx.x*256 + threadIdx.x;
  if (e < N_EDGES){
    int pos = atomicAdd(&cursor[dst[e]], 1);
    csr_src[pos] = src[e];
  }
}

// ---------------- prep: wcat (fp32->bf16 concat) + copy_x + zero scratch ----------------
#define NZERO 14656   // cnt(10048) + stats(4096) + bias0(512)
__global__ __launch_bounds__(256) void k_prep(const float* __restrict__ wpr, const float* __restrict__ wpo,
                                              const float* __restrict__ wrel, const float* __restrict__ wroot,
                                              const float* __restrict__ wfr, const float* __restrict__ wfo,
                                              const float* __restrict__ x,
                                              u16* __restrict__ Wcat, u16* __restrict__ Wfin,
                                              u16* __restrict__ A, u32* __restrict__ zreg){
  int b = blockIdx.x, t = threadIdx.x;
  if (b < 4096){
    int i = b*256 + t;
    int lyr = i >> 18;
    int r   = i & 262143;
    int o = r >> 9, k = r & 511;
    const float* R = (lyr==0) ? wpr : wrel  + (size_t)(lyr-1)*262144;
    const float* O = (lyr==0) ? wpo : wroot + (size_t)(lyr-1)*262144;
    Wcat[(size_t)lyr*524288 + (size_t)o*KDIM + k]        = f2bf(R[r]);
    Wcat[(size_t)lyr*524288 + (size_t)o*KDIM + HDIM + k] = f2bf(O[r]);
    if (i < 10*512){
      int oo = i >> 9, kk = i & 511;
      Wfin[oo*KDIM + kk]        = f2bf(wfr[i]);
      Wfin[oo*KDIM + HDIM + kk] = f2bf(wfo[i]);
    }
  } else if (b < 9096){
    int c = (b-4096)*256 + t;
    int n = c >> 7, o = (c & 127)*4;
    float4 v = *(const float4*)(x + (size_t)n*HDIM + o);
    ushort4 bb;
    bb.x = f2bf(v.x); bb.y = f2bf(v.y); bb.z = f2bf(v.z); bb.w = f2bf(v.w);
    *(ushort4*)(A + (size_t)n*KDIM + HDIM + o) = bb;
  } else {
    int i = (b-9096)*256 + t;
    if (i < NZERO) zreg[i] = 0u;
  }
}

// ================= XCD-paneled agg core =================
__device__ __forceinline__ void agg_panel2(int n, int pc, int li, const u16* __restrict__ Abuf,
                                           const int* __restrict__ row_ptr, const int* __restrict__ cnt,
                                           const int* __restrict__ csr, const float* __restrict__ inv_deg,
                                           float* __restrict__ a){
  int start = row_ptr[n], num = cnt[n];
  const u16* base = Abuf + HDIM + pc*128 + li*4;
  a[0]=0.f; a[1]=0.f; a[2]=0.f; a[3]=0.f;
  int s[8];
  #pragma unroll
  for (int i=0;i<8;i++) s[i] = (i < num) ? csr[start+i] : 0;
  int j = 0;
  while (j + 8 <= num){
    int cur[8];
    #pragma unroll
    for (int i=0;i<8;i++) cur[i] = s[i];
    int jn = j + 8;
    #pragma unroll
    for (int i=0;i<8;i++) s[i] = (jn+i < num) ? csr[start+jn+i] : 0;
    #pragma unroll
    for (int i=0;i<8;i++){
      uint2 v = *(const uint2*)(base + (size_t)cur[i]*KDIM);
      a[0]+=bflo(v.x); a[1]+=bfhi(v.x); a[2]+=bflo(v.y); a[3]+=bfhi(v.y);
    }
    j = jn;
  }
  #pragma unroll
  for (int i=0;i<8;i++){
    if (j+i < num){
      uint2 v = *(const uint2*)(base + (size_t)s[i]*KDIM);
      a[0]+=bflo(v.x); a[1]+=bfhi(v.x); a[2]+=bflo(v.y); a[3]+=bfhi(v.y);
    }
  }
  float id = inv_deg[n];
  #pragma unroll
  for (int i=0;i<4;i++) a[i] *= id;
}

// wscale row with fused BN finalize (whole block per row)
__device__ __forceinline__ void wscale_row(int o, const u16* __restrict__ Wsrc, const float* __restrict__ stats,
                                           const float* __restrict__ gamma, const float* __restrict__ beta,
                                           int layer, u16* __restrict__ Wdst, float* __restrict__ biasOut){
  __shared__ float wred[4];
  int t = threadIdx.x, l = t & 63, w = t >> 6;
  int k = t*4;
  int fk = k & 511;
  float a[4], b[4];
  #pragma unroll
  for (int i=0;i<4;i++){
    int f = fk + i;
    float mu  = stats[f] * (1.f/N_NODES);
    float var = stats[512+f] * (1.f/N_NODES) - mu*mu;
    float rs  = rsqrtf(var + 1e-5f);
    float g = gamma[layer*512+f];
    a[i] = g*rs;
    b[i] = beta[layer*512+f] - mu*a[i];
  }
  const u16* row = Wsrc + (size_t)o*KDIM;
  uint2 v = *(const uint2*)(row + k);
  float f0 = bflo(v.x), f1 = bfhi(v.x), f2 = bflo(v.y), f3 = bfhi(v.y);
  u16 od[4];
  od[0]=f2bf(f0*a[0]); od[1]=f2bf(f1*a[1]); od[2]=f2bf(f2*a[2]); od[3]=f2bf(f3*a[3]);
  *(ushort4*)(Wdst + (size_t)o*KDIM + k) = *(ushort4*)od;
  float bsum = f0*b[0] + f1*b[1] + f2*b[2] + f3*b[3];
  #pragma unroll
  for (int off=32; off; off>>=1) bsum += __shfl_down(bsum, off);
  if (l==0) wred[w] = bsum;
  __syncthreads();
  if (t==0) biasOut[o] = wred[0]+wred[1]+wred[2]+wred[3];
}

// ---------------- XCD-paneled agg: grid 5000 1D; pc = id&3 ----------------
__global__ __launch_bounds__(256) void k_agg(const u16* __restrict__ Abuf,
                                             const int* __restrict__ row_ptr, const int* __restrict__ cnt,
                                             const int* __restrict__ csr, const float* __restrict__ inv_deg,
                                             u16* __restrict__ Aleft){
  int id = blockIdx.x;
  int pc = id & 3, g = id >> 2;
  int t = threadIdx.x, w = t >> 6, l = t & 63, hf = l >> 5, li = l & 31;
  int n = g*8 + w*2 + hf;
  float a[4];
  agg_panel2(n, pc, li, Abuf, row_ptr, cnt, csr, inv_deg, a);
  ushort4 ob;
  ob.x = f2bf(a[0]); ob.y = f2bf(a[1]); ob.z = f2bf(a[2]); ob.w = f2bf(a[3]);
  *(ushort4*)(Aleft + (size_t)n*KDIM + pc*128 + li*4) = ob;
}

// ---------------- XCD-paneled agg + wscale (blocks id<512 scale weight row id) ----------------
__global__ __launch_bounds__(256) void k_aggws(const u16* __restrict__ Abuf,
                                               const int* __restrict__ row_ptr, const int* __restrict__ cnt,
                                               const int* __restrict__ csr, const float* __restrict__ inv_deg,
                                               u16* __restrict__ Aleft,
                                               const u16* __restrict__ Wsrc, const float* __restrict__ stats,
                                               const float* __restrict__ gamma, const float* __restrict__ beta,
                                               int layer, u16* __restrict__ Wdst, float* __restrict__ biasOut){
  int id = blockIdx.x;
  if (id < 512)
    wscale_row(id, Wsrc, stats, gamma, beta, layer, Wdst, biasOut);
  int pc = id & 3, g = id >> 2;
  int t = threadIdx.x, w = t >> 6, l = t & 63, hf = l >> 5, li = l & 31;
  int n = g*8 + w*2 + hf;
  float a[4];
  agg_panel2(n, pc, li, Abuf, row_ptr, cnt, csr, inv_deg, a);
  ushort4 ob;
  ob.x = f2bf(a[0]); ob.y = f2bf(a[1]); ob.z = f2bf(a[2]); ob.w = f2bf(a[3]);
  *(ushort4*)(Aleft + (size_t)n*KDIM + pc*128 + li*4) = ob;
}

// ---------------- k_pq: project h3 to 20 dims with inline BN-fold ----------------
__global__ __launch_bounds__(256) void k_pq(const u16* __restrict__ A,
                                            const u16* __restrict__ Wfin,
                                            const float* __restrict__ stats,
                                            const float* __restrict__ gamma, const float* __restrict__ beta,
                                            float* __restrict__ P, float* __restrict__ Q){
  __shared__ float sa[512], sb[512];
  __shared__ __align__(16) u16 sw[20*512];
  int t = threadIdx.x, w = t >> 6, l = t & 63;
  for (int k = t; k < 512; k += 256){
    float mu  = stats[k] * (1.f/N_NODES);
    float var = stats[512+k] * (1.f/N_NODES) - mu*mu;
    float rs  = rsqrtf(var + 1e-5f);
    float g = gamma[3*512+k];
    sa[k] = g*rs;
    sb[k] = beta[3*512+k] - mu*g*rs;
  }
  for (int i = t; i < 1280; i += 256){
    int c = (i*8) >> 9;
    int k = (i*8) & 511;
    const u16* srcp = (c < 10) ? (Wfin + (size_t)c*KDIM + k)
                               : (Wfin + (size_t)(c-10)*KDIM + HDIM + k);
    *(uint4*)(sw + i*8) = *(const uint4*)srcp;
  }
  __syncthreads();
  int n = blockIdx.x*4 + w;
  uint4 vh = *(const uint4*)(A + (size_t)n*KDIM + HDIM + l*8);
  float hh[8];
  {
    float hr[8] = { bflo(vh.x), bfhi(vh.x), bflo(vh.y), bfhi(vh.y),
                    bflo(vh.z), bfhi(vh.z), bflo(vh.w), bfhi(vh.w) };
    #pragma unroll
    for (int i=0;i<8;i++) hh[i] = hr[i]*sa[l*8+i] + sb[l*8+i];
  }
  float acc[20];
  #pragma unroll
  for (int c=0;c<20;c++){
    uint4 wv = *(const uint4*)(sw + c*512 + l*8);
    acc[c] = hh[0]*bflo(wv.x)+hh[1]*bfhi(wv.x)+hh[2]*bflo(wv.y)+hh[3]*bfhi(wv.y)
           + hh[4]*bflo(wv.z)+hh[5]*bfhi(wv.z)+hh[6]*bflo(wv.w)+hh[7]*bfhi(wv.w);
  }
  #pragma unroll
  for (int c=0;c<20;c++)
    #pragma unroll
    for (int off=32; off; off>>=1)
      acc[c] += __shfl_down(acc[c], off);
  if (l == 0){
    #pragma unroll
    for (int c=0;c<10;c++) P[n*10+c] = acc[c];
    #pragma unroll
    for (int c=0;c<10;c++) Q[n*10+c] = acc[10+c];
  }
}

// ---------------- k_aggout: mean-gather P (40B rows) + Q + log_softmax ----------------
__global__ __launch_bounds__(256) void k_aggout(const float* __restrict__ P, const float* __restrict__ Q,
                                                const int* __restrict__ row_ptr, const int* __restrict__ cnt,
                                                const int* __restrict__ csr, const float* __restrict__ inv_deg,
                                                float* __restrict__ out){
  __shared__ float red[4][12];
  int t = threadIdx.x, w = t >> 6, l = t & 63;
  int n = blockIdx.x*4 + w;
  float acc = 0.f;
  if (l < 10){
    int start = row_ptr[n], num = cnt[n];
    int s0 = (0 < num) ? csr[start] : 0;
    int s1 = (1 < num) ? csr[start+1] : 0;
    int j = 0;
    while (j + 2 <= num){
      int t0 = s0, t1 = s1;
      if (j+2 < num) s0 = csr[start+j+2];
      if (j+3 < num) s1 = csr[start+j+3];
      acc += P[t0*10 + l] + P[t1*10 + l];
      j += 2;
    }
    if (j < num) acc += P[s0*10 + l];
    acc = acc * inv_deg[n] + Q[n*10 + l];
    red[w][l] = acc;
  }
  __syncthreads();
  if (l == 0){
    float m = red[w][0];
    #pragma unroll
    for (int cc=1;cc<10;cc++) m = fmaxf(m, red[w][cc]);
    float s = 0.f;
    #pragma unroll
    for (int cc=0;cc<10;cc++) s += expf(red[w][cc]-m);
    red[w][10] = m + logf(s);
  }
  __syncthreads();
  if (l < 10) out[n*10 + l] = acc - red[w][10];
}

// ---------------- GEMM 64x128 tile, BK=32 (R13-proven), XCD A-partition ----------------
__global__ __launch_bounds__(256) void k_gemm(const u16* __restrict__ A, const u16* __restrict__ W,
                                              const float* __restrict__ bias,
                                              u16* __restrict__ Hout, float* __restrict__ stats){
  __shared__ __align__(16) u16 As[64*32];
  __shared__ __align__(16) u16 Bs[128*32];
  __shared__ float red_s[2][128];
  __shared__ float red_q[2][128];
  const int id  = blockIdx.x;
  const int xcd = id & 7;
  const int j   = id >> 3;
  const int m_idx = xcd*20 + (j>>2);
  const int pc  = j & 3;
  if (m_idx >= 158) return;
  const int t  = threadIdx.x;
  const int l  = t & 63;
  const int wv = t >> 6;
  const int wm = wv >> 1, wn = wv & 1;
  const int m0 = m_idx * 64;
  const int n0 = pc * 128;

  const int c1 = t + 256;
  const size_t gA  = (size_t)(m0 + (t>>2))*KDIM + ((t&3)*8);
  const size_t gB0 = (size_t)(n0 + (t>>2))*KDIM + ((t&3)*8);
  const size_t gB1 = (size_t)(n0 + (c1>>2))*KDIM + ((c1&3)*8);

  f32x4 acc[2][4];
  #pragma unroll
  for (int i=0;i<2;i++)
    #pragma unroll
    for (int jj=0;jj<4;jj++)
      acc[i][jj] = f32x4{0.f,0.f,0.f,0.f};

  const int aoff = (wm*32 + (l&15))*32 + (l>>4)*8;
  const int boff = (wn*64 + (l&15))*32 + (l>>4)*8;

  for (int k0 = 0; k0 < KDIM; k0 += 32){
    __builtin_amdgcn_global_load_lds((const __attribute__((address_space(1))) void*)(A + gA + k0),
                                     (__attribute__((address_space(3))) void*)(As + t*8), 16, 0, 0);
    __builtin_amdgcn_global_load_lds((const __attribute__((address_space(1))) void*)(W + gB0 + k0),
                                     (__attribute__((address_space(3))) void*)(Bs + t*8), 16, 0, 0);
    __builtin_amdgcn_global_load_lds((const __attribute__((address_space(1))) void*)(W + gB1 + k0),
                                     (__attribute__((address_space(3))) void*)(Bs + c1*8), 16, 0, 0);
    __syncthreads();
    bf16x8 af[2], bfr[4];
    af[0] = *(const bf16x8*)(As + aoff);
    af[1] = *(const bf16x8*)(As + aoff + 16*32);
    #pragma unroll
    for (int nt=0; nt<4; nt++)
      bfr[nt] = *(const bf16x8*)(Bs + boff + nt*16*32);
    #pragma unroll
    for (int mt=0; mt<2; mt++)
      #pragma unroll
      for (int nt=0; nt<4; nt++)
        acc[mt][nt] = __builtin_amdgcn_mfma_f32_16x16x32_bf16(af[mt], bfr[nt], acc[mt][nt], 0, 0, 0);
    __syncthreads();
  }

  float bi[4], sc[4], qc[4];
  #pragma unroll
  for (int nt=0; nt<4; nt++){
    bi[nt] = bias[n0 + wn*64 + nt*16 + (l & 15)];
    sc[nt] = 0.f; qc[nt] = 0.f;
  }
  #pragma unroll
  for (int nt=0; nt<4; nt++){
    const int col = n0 + wn*64 + nt*16 + (l & 15);
    #pragma unroll
    for (int mt=0; mt<2; mt++){
      #pragma unroll
      for (int r=0; r<4; r++){
        const int row = m0 + wm*32 + mt*16 + (l>>4)*4 + r;
        if (row < N_NODES){
          float v = acc[mt][nt][r] + bi[nt];
          v = v > 0.f ? v : 0.f;
          sc[nt] += v; qc[nt] += v*v;
          Hout[(size_t)row*KDIM + HDIM + col] = f2bf(v);
        }
      }
    }
  }
  #pragma unroll
  for (int nt=0; nt<4; nt++){
    float s = sc[nt], q = qc[nt];
    s += __shfl_xor(s, 16); s += __shfl_xor(s, 32);
    q += __shfl_xor(q, 16); q += __shfl_xor(q, 32);
    if (l < 16){
      red_s[wm][wn*64 + nt*16 + l] = s;
      red_q[wm][wn*64 + nt*16 + l] = q;
    }
  }
  __syncthreads();
  if (t < 128){
    atomicAdd(&stats[n0 + t],       red_s[0][t] + red_s[1][t]);
    atomicAdd(&stats[512 + n0 + t], red_q[0][t] + red_q[1][t]);
  }
}

extern "C" void kernel_launch(void* const* d_in, const int* in_sizes, int n_in,
                              void* d_out, int out_size, void* d_ws, size_t ws_size,
                              hipStream_t stream){
  (void)in_sizes; (void)n_in; (void)out_size; (void)ws_size;
  const float* x     = (const float*)d_in[0];
  const int*   eidx  = (const int*)d_in[1];
  const float* wpr   = (const float*)d_in[2];
  const float* wpo   = (const float*)d_in[3];
  const float* wrel  = (const float*)d_in[4];
  const float* wroot = (const float*)d_in[5];
  const float* gamma = (const float*)d_in[6];
  const float* beta  = (const float*)d_in[7];
  const float* wfr   = (const float*)d_in[8];
  const float* wfo   = (const float*)d_in[9];
  const int* src  = eidx;
  const int* dstv = eidx + N_EDGES;

  char* p = (char*)d_ws;
  auto carve = [&](size_t b){ char* q = p; p += (b + 255) & ~(size_t)255; return q; };
  u16*  A0      = (u16*)carve((size_t)NPAD*KDIM*2);
  u16*  A1      = (u16*)carve((size_t)NPAD*KDIM*2);
  u16*  Wcat    = (u16*)carve((size_t)4*HDIM*KDIM*2);
  u16*  Wfin    = (u16*)carve((size_t)10*KDIM*2);
  u16*  Wsc     = (u16*)carve((size_t)HDIM*KDIM*2);
  int*   zreg   = (int*)carve((size_t)NZERO*4);
  int*   cnt    = zreg;
  float* stats  = (float*)(zreg + 10048);
  float* bias0  = (float*)(zreg + 10048 + 4096);
  int*  row_ptr = (int*)carve((N_NODES+1)*4);
  int*  cursor  = (int*)carve(N_NODES*4);
  int*  csr     = (int*)carve(N_EDGES*4);
  float* inv_deg= (float*)carve(N_NODES*4);
  float* biasN  = (float*)carve(512*4);
  float* Pb     = (float*)carve((size_t)N_NODES*10*4);
  float* Qb     = (float*)carve((size_t)N_NODES*10*4);
  float* outp   = (float*)d_out;

  k_prep<<<9154, 256, 0, stream>>>(wpr, wpo, wrel, wroot, wfr, wfo, x, Wcat, Wfin, A0, (u32*)zreg);
  k_hist<<<(N_EDGES+255)/256, 256, 0, stream>>>(dstv, cnt);
  k_scan<<<1, 1024, 0, stream>>>(cnt, row_ptr, cursor, inv_deg);
  k_fill<<<(N_EDGES+255)/256, 256, 0, stream>>>(src, dstv, cursor, csr);
  k_agg<<<5000, 256, 0, stream>>>(A0, row_ptr, cnt, csr, inv_deg, A0);

  u16* Ain = A0; u16* Aout = A1;
  for (int lyr=0; lyr<4; lyr++){
    const u16* Wthis = (lyr==0) ? Wcat : Wsc;
    const float* bthis = (lyr==0) ? bias0 : biasN;
    k_gemm<<<640, 256, 0, stream>>>(Ain, Wthis, bthis, Aout, stats + lyr*1024);
    if (lyr < 3){
      k_aggws<<<5000, 256, 0, stream>>>(Aout, row_ptr, cnt, csr, inv_deg, Aout,
                                        Wcat + (size_t)(lyr+1)*HDIM*KDIM, stats + lyr*1024,
                                        gamma, beta, lyr, Wsc, biasN);
    } else {
      k_pq<<<2500, 256, 0, stream>>>(Aout, Wfin, stats + lyr*1024, gamma, beta, Pb, Qb);
      k_aggout<<<2500, 256, 0, stream>>>(Pb, Qb, row_ptr, cnt, csr, inv_deg, outp);
    }
    u16* tmp = Ain; Ain = Aout; Aout = tmp;
  }
}